// Round 2
// baseline (766.708 us; speedup 1.0000x reference)
//
#include <hip/hip_runtime.h>
#include <hip/hip_fp16.h>

// SelfWarp on MI355X, round 4.
//  K1 vf_kernel  : fused value+flow, now SOFTWARE-PIPELINED (T14 async-stage
//                  split). Per tile: issue next tile's 32 global loads BEFORE
//                  GEMM1, convert+LDS-write them AFTER GEMM2, into a double-
//                  buffered 2x16KB u-tile. Barriers are raw s_barrier with
//                  lgkmcnt(0)-only waits (no vmcnt(0) drain -> prefetch loads
//                  stay in flight across the whole compute phase).
//                  Weight fragments persistent in VGPRs; wave w owns output
//                  channels [w*32,+32) / flow ch [w*16,+16). 3 barriers/tile.
//  K2 warp_kernel: 4 pixels/thread (4 consecutive rows, same column) -> 4
//                  independent flow loads + 16 independent 8B gathers in
//                  flight (was 1+4; latency-bound at 24% HBM). Nontemporal
//                  output stores keep L2 for the value gathers. Bijective
//                  XCD swizzle keeps consecutive rows on one XCD's L2.
// ws: [0,134217728) value fp16 interleaved (b*32+head, pix, ci);
//     [+134217728,+67108864) flow packed u32 (lo16=x fp16, hi16=y fp16).

typedef unsigned short u16;
typedef unsigned int   u32;
using short8   = __attribute__((ext_vector_type(8))) short;   // 8 fp16
using f32x4    = __attribute__((ext_vector_type(4))) float;   // MFMA C/D
using ushort4v = __attribute__((ext_vector_type(4))) unsigned short;

#define HW     65536
#define NTILES 8192     // 524288 pixels / 64 per tile

__device__ __forceinline__ u16 f2h(float f) {
  return __half_as_ushort(__float2half(f));   // RNE
}
__device__ __forceinline__ float h2f(u16 h) {
  return __half2float(__ushort_as_half(h));
}

// raw barrier: waits only LDS ops; outstanding global loads stay in flight.
#define BAR_LGKM() do {                                      \
    asm volatile("s_waitcnt lgkmcnt(0)" ::: "memory");       \
    __builtin_amdgcn_s_barrier();                            \
    asm volatile("" ::: "memory");                           \
  } while (0)

// A/B fragment for mfma_16x16x32_f16 from fp32 row: lane (q,m15) holds
// row (blk*16+m15), k = kc*32 + q*8 .. +8.
__device__ __forceinline__ short8 frag_from_f32(const float* __restrict__ src) {
  float4 a = *(const float4*)src;
  float4 b = *(const float4*)(src + 4);
  short8 r;
  r[0] = (short)f2h(a.x); r[1] = (short)f2h(a.y);
  r[2] = (short)f2h(a.z); r[3] = (short)f2h(a.w);
  r[4] = (short)f2h(b.x); r[5] = (short)f2h(b.y);
  r[6] = (short)f2h(b.z); r[7] = (short)f2h(b.w);
  return r;
}

// issue the 32 coalesced u loads for one tile into registers (no wait here)
__device__ __forceinline__ void vf_load_tile(const float* __restrict__ u,
                                             int tile, int tid,
                                             float* __restrict__ r) {
  const int gbase = tile << 6;
  const float* ub = u + ((size_t)(gbase >> 16) << 23) + (gbase & 65535);
  const int p  = tid & 63;
  const int cb = (tid >> 6) << 3;
#pragma unroll
  for (int pass = 0; pass < 4; ++pass)
#pragma unroll
    for (int j = 0; j < 8; ++j)
      r[pass * 8 + j] = ub[(size_t)(cb + pass * 32 + j) * HW + p];
}

// convert + swizzled LDS write of a staged tile ([px 64][ch 128] fp16,
// 16B chunk c of row p at slot c ^ (p&15))
__device__ __forceinline__ void vf_write_tile(u16* __restrict__ buf, int tid,
                                              const float* __restrict__ r) {
  const int p  = tid & 63;
  const int cb = (tid >> 6) << 3;
#pragma unroll
  for (int pass = 0; pass < 4; ++pass) {
    int c0 = cb + pass * 32;
    uint4 pk;
    pk.x = (u32)f2h(r[pass * 8 + 0]) | ((u32)f2h(r[pass * 8 + 1]) << 16);
    pk.y = (u32)f2h(r[pass * 8 + 2]) | ((u32)f2h(r[pass * 8 + 3]) << 16);
    pk.z = (u32)f2h(r[pass * 8 + 4]) | ((u32)f2h(r[pass * 8 + 5]) << 16);
    pk.w = (u32)f2h(r[pass * 8 + 6]) | ((u32)f2h(r[pass * 8 + 7]) << 16);
    *(uint4*)((char*)buf + p * 256 + (((c0 >> 3) ^ (p & 15)) << 4)) = pk;
  }
}

// ---------------------------------------------------------------------------
__global__ __launch_bounds__(256, 2) void vf_kernel(
    const float* __restrict__ u,  const float* __restrict__ w1,
    const float* __restrict__ b1, const float* __restrict__ w2,
    const float* __restrict__ b2, const float* __restrict__ wv,
    const float* __restrict__ bv, u16* __restrict__ vout,
    u32* __restrict__ fout)
{
  __shared__ u16 t_lds[2][64 * 128];   // 2 x 16 KB double buffer

  const int tid  = threadIdx.x;
  const int lane = tid & 63;
  const int w    = tid >> 6;        // wave id: owns ch [w*32,+32), fc [w*16,+16)
  const int m15  = lane & 15;
  const int q    = lane >> 4;

  // -- persistent weight fragments (tile-invariant, 80 VGPRs) --
  short8 w1f[2][4], wvf[2][4], w2f[4];
#pragma unroll
  for (int nt = 0; nt < 2; ++nt)
#pragma unroll
    for (int kc = 0; kc < 4; ++kc) {
      const int row = w * 32 + nt * 16 + m15;
      w1f[nt][kc] = frag_from_f32(w1 + row * 128 + kc * 32 + q * 8);
      wvf[nt][kc] = frag_from_f32(wv + row * 128 + kc * 32 + q * 8);
    }
#pragma unroll
  for (int kc = 0; kc < 4; ++kc)
    w2f[kc] = frag_from_f32(w2 + (w * 16 + m15) * 128 + kc * 32 + q * 8);

  // -- per-lane bias vectors: lane's 4 consecutive channels (q*4 + 0..3) --
  f32x4 vbias[2], hbias[2], fbias;
#pragma unroll
  for (int nt = 0; nt < 2; ++nt) {
    vbias[nt] = *(const f32x4*)(bv + w * 32 + nt * 16 + q * 4);
    hbias[nt] = *(const f32x4*)(b1 + w * 32 + nt * 16 + q * 4);
  }
  fbias = *(const f32x4*)(b2 + w * 16 + q * 4);

  const int step = (int)gridDim.x;
  int tile = blockIdx.x;
  float sreg[32];

  // prologue: stage tile0
  vf_load_tile(u, tile, tid, sreg);
  vf_write_tile(t_lds[0], tid, sreg);
  BAR_LGKM();

  int cur = 0;
  for (; tile < NTILES; ) {
    const int gbase = tile << 6;
    const int b     = gbase >> 16;        // tiles never cross batch
    const int img   = gbase & 65535;
    const int nxt   = tile + step;
    const bool have_next = (nxt < NTILES);

    if (have_next) vf_load_tile(u, nxt, tid, sreg);   // issue only; no wait

    // -- GEMM1: hmid(128ch) and value(128ch) for 64 px; wave owns 32 ch --
    f32x4 zero = {0.f, 0.f, 0.f, 0.f};
    f32x4 hm[2][4], va[2][4];
#pragma unroll
    for (int nt = 0; nt < 2; ++nt)
#pragma unroll
      for (int pxb = 0; pxb < 4; ++pxb) { hm[nt][pxb] = zero; va[nt][pxb] = zero; }

#pragma unroll
    for (int kc = 0; kc < 4; ++kc) {
      short8 uf[4];
#pragma unroll
      for (int pxb = 0; pxb < 4; ++pxb)
        uf[pxb] = *(const short8*)((const char*)t_lds[cur] +
                                   (pxb * 16 + m15) * 256 +
                                   ((((kc << 2) + q) ^ m15) << 4));
#pragma unroll
      for (int pxb = 0; pxb < 4; ++pxb)
#pragma unroll
        for (int nt = 0; nt < 2; ++nt) {
          hm[nt][pxb] = __builtin_amdgcn_mfma_f32_16x16x32_f16(
              w1f[nt][kc], uf[pxb], hm[nt][pxb], 0, 0, 0);
          va[nt][pxb] = __builtin_amdgcn_mfma_f32_16x16x32_f16(
              wvf[nt][kc], uf[pxb], va[nt][pxb], 0, 0, 0);
        }
    }
    BAR_LGKM();   // all u-tile reads done; buf[cur] becomes hmid

    // -- hmid: relu(h+b) -> buf[cur], 4 consecutive ch per lane = b64 write --
#pragma unroll
    for (int nt = 0; nt < 2; ++nt) {
      const int ch0   = w * 32 + nt * 16 + q * 4;
      const int chunk = ch0 >> 3;
      const int inner = (ch0 & 7) << 1;
#pragma unroll
      for (int pxb = 0; pxb < 4; ++pxb) {
        const int px = pxb * 16 + m15;
        float h0 = fmaxf(hm[nt][pxb][0] + hbias[nt][0], 0.f);
        float h1 = fmaxf(hm[nt][pxb][1] + hbias[nt][1], 0.f);
        float h2 = fmaxf(hm[nt][pxb][2] + hbias[nt][2], 0.f);
        float h3 = fmaxf(hm[nt][pxb][3] + hbias[nt][3], 0.f);
        uint2 pk;
        pk.x = (u32)f2h(h0) | ((u32)f2h(h1) << 16);
        pk.y = (u32)f2h(h2) | ((u32)f2h(h3) << 16);
        *(uint2*)((char*)t_lds[cur] + px * 256 + ((chunk ^ (px & 15)) << 4) +
                  inner) = pk;
      }
    }

    // -- value epilogue: direct interleaved store (head = ch>>2, ci = reg) --
#pragma unroll
    for (int nt = 0; nt < 2; ++nt) {
      const int head = w * 8 + nt * 4 + q;
#pragma unroll
      for (int pxb = 0; pxb < 4; ++pxb) {
        f32x4 v = va[nt][pxb];
        uint2 pk;
        pk.x = (u32)f2h(v[0] + vbias[nt][0]) | ((u32)f2h(v[1] + vbias[nt][1]) << 16);
        pk.y = (u32)f2h(v[2] + vbias[nt][2]) | ((u32)f2h(v[3] + vbias[nt][3]) << 16);
        *(uint2*)(vout + ((((size_t)(b * 32 + head)) << 16) + img +
                          pxb * 16 + m15) * 4) = pk;
      }
    }
    BAR_LGKM();   // hmid visible

    // -- GEMM2: flow(64 fc) for 64 px; wave owns 16 fc --
    f32x4 fl[4];
#pragma unroll
    for (int pxb = 0; pxb < 4; ++pxb) fl[pxb] = zero;
#pragma unroll
    for (int kc = 0; kc < 4; ++kc)
#pragma unroll
      for (int pxb = 0; pxb < 4; ++pxb) {
        short8 hf = *(const short8*)((const char*)t_lds[cur] +
                                     (pxb * 16 + m15) * 256 +
                                     ((((kc << 2) + q) ^ m15) << 4));
        fl[pxb] = __builtin_amdgcn_mfma_f32_16x16x32_f16(
            w2f[kc], hf, fl[pxb], 0, 0, 0);
      }

    // -- flow epilogue: lane holds (x,y) for heads h0, h0+1 of one pixel --
#pragma unroll
    for (int pxb = 0; pxb < 4; ++pxb) {
      f32x4 v = fl[pxb];
      const int h0 = w * 8 + q * 2;
      u32 pa = (u32)f2h(v[0] + fbias[0]) | ((u32)f2h(v[1] + fbias[1]) << 16);
      u32 pb = (u32)f2h(v[2] + fbias[2]) | ((u32)f2h(v[3] + fbias[3]) << 16);
      u32* fp = fout + (((size_t)(b * 32 + h0)) << 16) + img + pxb * 16 + m15;
      fp[0]  = pa;        // head h0
      fp[HW] = pb;        // head h0+1
    }

    // -- write staged next tile into the other buffer (waits land here) --
    if (have_next) vf_write_tile(t_lds[cur ^ 1], tid, sreg);
    BAR_LGKM();   // GEMM2 reads + staging writes done before next iteration
    cur ^= 1;
    tile = nxt;
  }
}

// ---------------------------------------------------------------------------
__global__ __launch_bounds__(256) void warp_kernel(
    const u16* __restrict__ value, const u32* __restrict__ flow,
    float* __restrict__ out)
{
  // 16384 blocks; block covers 4 consecutive rows x 256 cols of one
  // head-image. Bijective XCD swizzle (16384 % 8 == 0): XCD x runs logical
  // blocks [x*2048,(x+1)*2048) in order -> tap rows y/y+1 stay in its L2.
  const int P   = blockIdx.x;
  const int L   = ((P & 7) << 11) | (P >> 3);
  const int hb  = L >> 6;                      // b*32 + head
  const int g   = L & 63;                      // rows 4g .. 4g+3
  const int col = threadIdx.x;

  const u16* vb = value + ((size_t)hb << 18);
  const u32* fp = flow + ((size_t)hb << 16) + (g << 10) + col;

  u32 f[4];
#pragma unroll
  for (int r = 0; r < 4; ++r) f[r] = fp[r << 8];   // 4 independent loads

  float w00[4], w01[4], w10[4], w11[4];
  ushort4v t00[4], t01[4], t10[4], t11[4];
#pragma unroll
  for (int r = 0; r < 4; ++r) {
    float fx = h2f((u16)(f[r] & 0xffffu));
    float fy = h2f((u16)(f[r] >> 16));
    const int hq = (g << 2) + r;
    float gx = -1.f + (2.f / 255.f) * (float)col + fx;
    float gy = -1.f + (2.f / 255.f) * (float)hq + fy;
    float pxr = ((gx + 1.f) * 256.f - 1.f) * 0.5f;
    float pyr = ((gy + 1.f) * 256.f - 1.f) * 0.5f;
    float px = pxr - floorf(pxr * (1.f / 256.f)) * 256.f;
    float py = pyr - floorf(pyr * (1.f / 256.f)) * 256.f;
    if (px >= 256.f) px -= 256.f;   // rounding guard
    if (py >= 256.f) py -= 256.f;
    if (px < 0.f) px = 0.f;
    if (py < 0.f) py = 0.f;
    float x0f = floorf(px), y0f = floorf(py);
    float wx = px - x0f, wy = py - y0f;
    int x0 = (int)x0f; if (x0 > 255) x0 = 255;
    int y0 = (int)y0f; if (y0 > 255) y0 = 255;
    int x1 = (x0 + 1) & 255;
    int y1 = (y0 + 1) & 255;
    w00[r] = (1.f - wx) * (1.f - wy);
    w01[r] = wx * (1.f - wy);
    w10[r] = (1.f - wx) * wy;
    w11[r] = wx * wy;
    // 16 independent 8B gathers across the 4 rows (one tap = 4 channels)
    t00[r] = *(const ushort4v*)(vb + ((y0 * 256 + x0) << 2));
    t01[r] = *(const ushort4v*)(vb + ((y0 * 256 + x1) << 2));
    t10[r] = *(const ushort4v*)(vb + ((y1 * 256 + x0) << 2));
    t11[r] = *(const ushort4v*)(vb + ((y1 * 256 + x1) << 2));
  }

  float* ob = out + ((size_t)hb << 18) + (g << 10) + col;
#pragma unroll
  for (int r = 0; r < 4; ++r)
#pragma unroll
    for (int ci = 0; ci < 4; ++ci) {
      float res = w00[r] * h2f(t00[r][ci]) + w01[r] * h2f(t01[r][ci])
                + w10[r] * h2f(t10[r][ci]) + w11[r] * h2f(t11[r][ci]);
      // output never re-read: nontemporal keeps L2 for the value gathers
      __builtin_nontemporal_store(res, ob + (r << 8) + ((size_t)ci << 16));
    }
}

// ---------------------------------------------------------------------------
extern "C" void kernel_launch(void* const* d_in, const int* in_sizes, int n_in,
                              void* d_out, int out_size, void* d_ws, size_t ws_size,
                              hipStream_t stream) {
  const float* u  = (const float*)d_in[0];
  const float* w1 = (const float*)d_in[1];
  const float* b1 = (const float*)d_in[2];
  const float* w2 = (const float*)d_in[3];
  const float* b2 = (const float*)d_in[4];
  const float* wv = (const float*)d_in[5];
  const float* bv = (const float*)d_in[6];

  u16* value_ws = (u16*)d_ws;                        // 134,217,728 B
  u32* flow_ws  = (u32*)((char*)d_ws + 134217728);   //  67,108,864 B
  float* out    = (float*)d_out;

  // 512 blocks = 2 resident blocks/CU (32 KB LDS, <=256 VGPR), 16 tiles each
  vf_kernel<<<dim3(512), dim3(256), 0, stream>>>(u, w1, b1, w2, b2, wv, bv,
                                                 value_ws, flow_ws);
  warp_kernel<<<dim3(16384), dim3(256), 0, stream>>>(value_ws, flow_ws, out);
}

// Round 3
// 623.539 us; speedup vs baseline: 1.2296x; 1.2296x over previous
//
#include <hip/hip_runtime.h>
#include <hip/hip_fp16.h>

// SelfWarp on MI355X, round 5.
//  K1 vf_kernel  : fused value+flow, pipelined via global_load_lds (direct
//                  HBM->LDS DMA, ZERO register footprint for staging — fixes
//                  round-4's spill regression at VGPR_Count=128). Per tile:
//                  issue 8 global_load_lds_dwordx4/wave for tile t+1 into a
//                  double-buffered linear fp32 [ch][px] buffer, then counted
//                  s_waitcnt vmcnt(8) (tile t's loads are the oldest 8) —
//                  tile t+1's loads stay in flight across the whole body.
//                  A small LDS->LDS convert pass (conflict-free ds_read_b32 +
//                  swizzled ds_write_b128) produces the fp16 tile the proven
//                  GEMM path consumes. 4 barriers/tile, no vmcnt(0) drain.
//                  LDS 80 KB -> 2 blocks/CU (grid 512 = 2/CU).
//  K2 warp_kernel: 8 rows x 256 cols per block (8192 blocks), two 4-row
//                  batches per thread -> 8 flow loads + 16 gathers in flight
//                  while staying under 128 VGPR (4 waves/SIMD). 8-row tap
//                  window fits L1. Bijective XCD swizzle keeps consecutive
//                  row-groups of a head on one XCD's L2. NT output stores.
// ws: [0,134217728) value fp16 interleaved (b*32+head, pix, ci);
//     [+134217728,+67108864) flow packed u32 (lo16=x fp16, hi16=y fp16).

typedef unsigned short u16;
typedef unsigned int   u32;
using short8   = __attribute__((ext_vector_type(8))) short;   // 8 fp16
using f32x4    = __attribute__((ext_vector_type(4))) float;   // MFMA C/D
using ushort4v = __attribute__((ext_vector_type(4))) unsigned short;

#define HW     65536
#define NTILES 8192     // 524288 pixels / 64 per tile

__device__ __forceinline__ u16 f2h(float f) {
  return __half_as_ushort(__float2half(f));   // RNE
}
__device__ __forceinline__ float h2f(u16 h) {
  return __half2float(__ushort_as_half(h));
}

// raw barrier: waits only LDS ops; outstanding global ops stay in flight.
#define BAR_LGKM() do {                                      \
    asm volatile("s_waitcnt lgkmcnt(0)" ::: "memory");       \
    __builtin_amdgcn_s_barrier();                            \
    asm volatile("" ::: "memory");                           \
  } while (0)

// A/B fragment for mfma_16x16x32_f16 from fp32 row: lane (q,m15) holds
// row (blk*16+m15), k = kc*32 + q*8 .. +8.
__device__ __forceinline__ short8 frag_from_f32(const float* __restrict__ src) {
  float4 a = *(const float4*)src;
  float4 b = *(const float4*)(src + 4);
  short8 r;
  r[0] = (short)f2h(a.x); r[1] = (short)f2h(a.y);
  r[2] = (short)f2h(a.z); r[3] = (short)f2h(a.w);
  r[4] = (short)f2h(b.x); r[5] = (short)f2h(b.y);
  r[6] = (short)f2h(b.z); r[7] = (short)f2h(b.w);
  return r;
}

// issue one tile's 32 KB of u as 8 global_load_lds_dwordx4 per wave into a
// LINEAR fp32 [ch 128][px 64] LDS buffer. Lane l's 16 B lands at
// base + l*16 = (ch0 + (l>>4))*256B + (l&15)*16B — matching the global
// source addr ub + (ch0 + (l>>4))*HW + (l&15)*4. No registers consumed.
__device__ __forceinline__ void vf_issue_tile(const float* __restrict__ u,
                                              int tile, int tid,
                                              float* __restrict__ sbuf) {
  const int gbase = tile << 6;
  const int wave  = tid >> 6;
  const int lane  = tid & 63;
  const float* ub = u + ((size_t)(gbase >> 16) << 23) + (gbase & 65535)
                      + (size_t)(lane >> 4) * HW + ((lane & 15) << 2);
#pragma unroll
  for (int i = 0; i < 8; ++i) {
    const int ch0 = wave * 32 + i * 4;
    __builtin_amdgcn_global_load_lds(
        (const __attribute__((address_space(1))) void*)(ub + (size_t)ch0 * HW),
        (__attribute__((address_space(3))) void*)(sbuf + ch0 * 64),
        16, 0, 0);
  }
}

// LDS->LDS convert: fp32 linear [ch][px] -> fp16 swizzled [px][ch]
// (16B chunk c of row p at slot c ^ (p&15)). Reads: lanes have consecutive
// p at fixed ch -> 2-way bank alias (free). 32 ds_read_b32 + 4 ds_write_b128.
__device__ __forceinline__ void vf_convert(const float* __restrict__ sbuf,
                                           u16* __restrict__ T, int tid) {
  const int p  = tid & 63;
  const int cb = (tid >> 6) << 3;
#pragma unroll
  for (int pass = 0; pass < 4; ++pass) {
    const int c0 = cb + pass * 32;
    const float* rp = sbuf + c0 * 64 + p;
    uint4 pk;
    pk.x = (u32)f2h(rp[0])   | ((u32)f2h(rp[64])  << 16);
    pk.y = (u32)f2h(rp[128]) | ((u32)f2h(rp[192]) << 16);
    pk.z = (u32)f2h(rp[256]) | ((u32)f2h(rp[320]) << 16);
    pk.w = (u32)f2h(rp[384]) | ((u32)f2h(rp[448]) << 16);
    *(uint4*)((char*)T + p * 256 + (((c0 >> 3) ^ (p & 15)) << 4)) = pk;
  }
}

// ---------------------------------------------------------------------------
__global__ __launch_bounds__(256, 2) void vf_kernel(
    const float* __restrict__ u,  const float* __restrict__ w1,
    const float* __restrict__ b1, const float* __restrict__ w2,
    const float* __restrict__ b2, const float* __restrict__ wv,
    const float* __restrict__ bv, u16* __restrict__ vout,
    u32* __restrict__ fout)
{
  __shared__ float S[2][128 * 64];  // 2 x 32 KB fp32 staging (linear [ch][px])
  __shared__ u16   T[64 * 128];     // 16 KB fp16 tile: u16 tile, then hmid

  const int tid  = threadIdx.x;
  const int lane = tid & 63;
  const int w    = tid >> 6;        // wave id: owns ch [w*32,+32), fc [w*16,+16)
  const int m15  = lane & 15;
  const int q    = lane >> 4;

  // -- persistent weight fragments (tile-invariant, 80 VGPRs) --
  short8 w1f[2][4], wvf[2][4], w2f[4];
#pragma unroll
  for (int nt = 0; nt < 2; ++nt)
#pragma unroll
    for (int kc = 0; kc < 4; ++kc) {
      const int row = w * 32 + nt * 16 + m15;
      w1f[nt][kc] = frag_from_f32(w1 + row * 128 + kc * 32 + q * 8);
      wvf[nt][kc] = frag_from_f32(wv + row * 128 + kc * 32 + q * 8);
    }
#pragma unroll
  for (int kc = 0; kc < 4; ++kc)
    w2f[kc] = frag_from_f32(w2 + (w * 16 + m15) * 128 + kc * 32 + q * 8);

  // -- per-lane bias vectors: lane's 4 consecutive channels (q*4 + 0..3) --
  f32x4 vbias[2], hbias[2], fbias;
#pragma unroll
  for (int nt = 0; nt < 2; ++nt) {
    vbias[nt] = *(const f32x4*)(bv + w * 32 + nt * 16 + q * 4);
    hbias[nt] = *(const f32x4*)(b1 + w * 32 + nt * 16 + q * 4);
  }
  fbias = *(const f32x4*)(b2 + w * 16 + q * 4);

  const int step = (int)gridDim.x;
  float* Sc = &S[0][0];
  float* Sn = &S[1][0];

  // prologue: issue tile0's loads (async)
  vf_issue_tile(u, blockIdx.x, tid, Sc);

  for (int tile = blockIdx.x; tile < NTILES; tile += step) {
    const int gbase = tile << 6;
    const int b     = gbase >> 16;        // tiles never cross batch
    const int img   = gbase & 65535;
    const int nxt   = tile + step;
    const bool have_next = (nxt < NTILES);

    if (have_next) vf_issue_tile(u, nxt, tid, Sn);   // async into other buffer

    // wait for THIS tile's 8 loads (oldest); keep next tile's 8 in flight.
    if (have_next) {
      asm volatile("s_waitcnt vmcnt(8)" ::: "memory");
    } else {
      asm volatile("s_waitcnt vmcnt(0)" ::: "memory");
    }
    __builtin_amdgcn_s_barrier();        // all waves' tile data landed; also
    __builtin_amdgcn_sched_barrier(0);   // prev GEMM2's T reads are done

    vf_convert(Sc, T, tid);              // fp32 [ch][px] -> fp16 swizzled tile
    BAR_LGKM();                          // T visible

    // -- GEMM1: hmid(128ch) and value(128ch) for 64 px; wave owns 32 ch --
    f32x4 zero = {0.f, 0.f, 0.f, 0.f};
    f32x4 hm[2][4], va[2][4];
#pragma unroll
    for (int nt = 0; nt < 2; ++nt)
#pragma unroll
      for (int pxb = 0; pxb < 4; ++pxb) { hm[nt][pxb] = zero; va[nt][pxb] = zero; }

#pragma unroll
    for (int kc = 0; kc < 4; ++kc) {
      short8 uf[4];
#pragma unroll
      for (int pxb = 0; pxb < 4; ++pxb)
        uf[pxb] = *(const short8*)((const char*)T + (pxb * 16 + m15) * 256 +
                                   ((((kc << 2) + q) ^ m15) << 4));
#pragma unroll
      for (int pxb = 0; pxb < 4; ++pxb)
#pragma unroll
        for (int nt = 0; nt < 2; ++nt) {
          hm[nt][pxb] = __builtin_amdgcn_mfma_f32_16x16x32_f16(
              w1f[nt][kc], uf[pxb], hm[nt][pxb], 0, 0, 0);
          va[nt][pxb] = __builtin_amdgcn_mfma_f32_16x16x32_f16(
              wvf[nt][kc], uf[pxb], va[nt][pxb], 0, 0, 0);
        }
    }
    BAR_LGKM();   // all u-tile reads done; T becomes hmid

    // -- hmid: relu(h+b) -> T, 4 consecutive ch per lane = one b64 write --
#pragma unroll
    for (int nt = 0; nt < 2; ++nt) {
      const int ch0   = w * 32 + nt * 16 + q * 4;
      const int chunk = ch0 >> 3;
      const int inner = (ch0 & 7) << 1;
#pragma unroll
      for (int pxb = 0; pxb < 4; ++pxb) {
        const int px = pxb * 16 + m15;
        float h0 = fmaxf(hm[nt][pxb][0] + hbias[nt][0], 0.f);
        float h1 = fmaxf(hm[nt][pxb][1] + hbias[nt][1], 0.f);
        float h2 = fmaxf(hm[nt][pxb][2] + hbias[nt][2], 0.f);
        float h3 = fmaxf(hm[nt][pxb][3] + hbias[nt][3], 0.f);
        uint2 pk;
        pk.x = (u32)f2h(h0) | ((u32)f2h(h1) << 16);
        pk.y = (u32)f2h(h2) | ((u32)f2h(h3) << 16);
        *(uint2*)((char*)T + px * 256 + ((chunk ^ (px & 15)) << 4) + inner) = pk;
      }
    }

    // -- value epilogue: direct interleaved store (head = ch>>2, ci = reg) --
#pragma unroll
    for (int nt = 0; nt < 2; ++nt) {
      const int head = w * 8 + nt * 4 + q;
#pragma unroll
      for (int pxb = 0; pxb < 4; ++pxb) {
        f32x4 v = va[nt][pxb];
        uint2 pk;
        pk.x = (u32)f2h(v[0] + vbias[nt][0]) | ((u32)f2h(v[1] + vbias[nt][1]) << 16);
        pk.y = (u32)f2h(v[2] + vbias[nt][2]) | ((u32)f2h(v[3] + vbias[nt][3]) << 16);
        *(uint2*)(vout + ((((size_t)(b * 32 + head)) << 16) + img +
                          pxb * 16 + m15) * 4) = pk;
      }
    }
    BAR_LGKM();   // hmid visible

    // -- GEMM2: flow(64 fc) for 64 px; wave owns 16 fc --
    f32x4 fl[4];
#pragma unroll
    for (int pxb = 0; pxb < 4; ++pxb) fl[pxb] = zero;
#pragma unroll
    for (int kc = 0; kc < 4; ++kc)
#pragma unroll
      for (int pxb = 0; pxb < 4; ++pxb) {
        short8 hf = *(const short8*)((const char*)T + (pxb * 16 + m15) * 256 +
                                     ((((kc << 2) + q) ^ m15) << 4));
        fl[pxb] = __builtin_amdgcn_mfma_f32_16x16x32_f16(
            w2f[kc], hf, fl[pxb], 0, 0, 0);
      }

    // -- flow epilogue: lane holds (x,y) for heads h0, h0+1 of one pixel --
#pragma unroll
    for (int pxb = 0; pxb < 4; ++pxb) {
      f32x4 v = fl[pxb];
      const int h0 = w * 8 + q * 2;
      u32 pa = (u32)f2h(v[0] + fbias[0]) | ((u32)f2h(v[1] + fbias[1]) << 16);
      u32 pb = (u32)f2h(v[2] + fbias[2]) | ((u32)f2h(v[3] + fbias[3]) << 16);
      u32* fp = fout + (((size_t)(b * 32 + h0)) << 16) + img + pxb * 16 + m15;
      fp[0]  = pa;        // head h0
      fp[HW] = pb;        // head h0+1
    }

    float* t = Sc; Sc = Sn; Sn = t;   // swap staging buffers
    // loop-top barrier separates these GEMM2 T-reads from next convert write
  }
}

// ---------------------------------------------------------------------------
__global__ __launch_bounds__(256) void warp_kernel(
    const u16* __restrict__ value, const u32* __restrict__ flow,
    float* __restrict__ out)
{
  // 8192 blocks; block covers 8 consecutive rows x 256 cols of one
  // head-image. Bijective XCD swizzle (8192 % 8 == 0): XCD x runs logical
  // blocks [x*1024,(x+1)*1024) in order -> one head's value (512 KB) stays
  // resident in its XCD L2 across the 32 blocks that consume it.
  const int P   = blockIdx.x;
  const int L   = ((P & 7) << 10) | (P >> 3);
  const int hb  = L >> 5;                      // b*32 + head
  const int g   = L & 31;                      // rows 8g .. 8g+7
  const int col = threadIdx.x;

  const u16* vb = value + ((size_t)hb << 18);
  const u32* fp = flow + ((size_t)hb << 16) + (g << 11) + col;

  u32 f[8];
#pragma unroll
  for (int r = 0; r < 8; ++r) f[r] = fp[r << 8];   // 8 independent loads

  const float cbase = (float)col * (256.f / 255.f) - 0.5f;
  float* ob = out + ((size_t)hb << 18) + (g << 11) + col;

#pragma unroll
  for (int half = 0; half < 2; ++half) {       // 2 batches of 4 rows keeps
    float w00[4], w01[4], w10[4], w11[4];      // VGPR < 128 (4 waves/SIMD)
    ushort4v t00[4], t01[4], t10[4], t11[4];
#pragma unroll
    for (int j = 0; j < 4; ++j) {
      const int r  = half * 4 + j;
      const int hq = (g << 3) + r;
      float fx = h2f((u16)(f[r] & 0xffffu));
      float fy = h2f((u16)(f[r] >> 16));
      // pxr = ((gx+1)*256-1)/2 with gx = -1 + (2/255)col + fx, folded:
      float pxr = fmaf(fx, 128.f, cbase);
      float pyr = fmaf(fy, 128.f, (float)hq * (256.f / 255.f) - 0.5f);
      float px = pxr - floorf(pxr * (1.f / 256.f)) * 256.f;
      float py = pyr - floorf(pyr * (1.f / 256.f)) * 256.f;
      if (px >= 256.f) px -= 256.f;   // rounding guard
      if (py >= 256.f) py -= 256.f;
      if (px < 0.f) px = 0.f;
      if (py < 0.f) py = 0.f;
      float x0f = floorf(px), y0f = floorf(py);
      float wx = px - x0f, wy = py - y0f;
      int x0 = (int)x0f; if (x0 > 255) x0 = 255;
      int y0 = (int)y0f; if (y0 > 255) y0 = 255;
      int x1 = (x0 + 1) & 255;
      int y1 = (y0 + 1) & 255;
      w00[j] = (1.f - wx) * (1.f - wy);
      w01[j] = wx * (1.f - wy);
      w10[j] = (1.f - wx) * wy;
      w11[j] = wx * wy;
      // 16 independent 8B gathers in flight (one tap = 4 channels)
      t00[j] = *(const ushort4v*)(vb + ((y0 * 256 + x0) << 2));
      t01[j] = *(const ushort4v*)(vb + ((y0 * 256 + x1) << 2));
      t10[j] = *(const ushort4v*)(vb + ((y1 * 256 + x0) << 2));
      t11[j] = *(const ushort4v*)(vb + ((y1 * 256 + x1) << 2));
    }
#pragma unroll
    for (int j = 0; j < 4; ++j) {
      const int r = half * 4 + j;
#pragma unroll
      for (int ci = 0; ci < 4; ++ci) {
        float res = w00[j] * h2f(t00[j][ci]) + w01[j] * h2f(t01[j][ci])
                  + w10[j] * h2f(t10[j][ci]) + w11[j] * h2f(t11[j][ci]);
        // output never re-read: NT store keeps L2 for the value gathers
        __builtin_nontemporal_store(res, ob + (r << 8) + ((size_t)ci << 16));
      }
    }
  }
}

// ---------------------------------------------------------------------------
extern "C" void kernel_launch(void* const* d_in, const int* in_sizes, int n_in,
                              void* d_out, int out_size, void* d_ws, size_t ws_size,
                              hipStream_t stream) {
  const float* u  = (const float*)d_in[0];
  const float* w1 = (const float*)d_in[1];
  const float* b1 = (const float*)d_in[2];
  const float* w2 = (const float*)d_in[3];
  const float* b2 = (const float*)d_in[4];
  const float* wv = (const float*)d_in[5];
  const float* bv = (const float*)d_in[6];

  u16* value_ws = (u16*)d_ws;                        // 134,217,728 B
  u32* flow_ws  = (u32*)((char*)d_ws + 134217728);   //  67,108,864 B
  float* out    = (float*)d_out;

  // vf: 512 blocks = 2 resident blocks/CU (80 KB LDS), 16 tiles each
  vf_kernel<<<dim3(512), dim3(256), 0, stream>>>(u, w1, b1, w2, b2, wv, bv,
                                                 value_ws, flow_ws);
  warp_kernel<<<dim3(8192), dim3(256), 0, stream>>>(value_ws, flow_ws, out);
}